// Round 13
// baseline (161.460 us; speedup 1.0000x reference)
//
#include <hip/hip_runtime.h>

typedef unsigned short ushort_t;
typedef unsigned int uint_t;

typedef __bf16 bf16x8 __attribute__((ext_vector_type(8)));
typedef float f32x4 __attribute__((ext_vector_type(4)));

#define KK 588       // true K
#define KP 608       // padded K (19 * 32)
#define NN 1152      // N (output cols)
#define MM 32768     // M (output rows)
#define POSROWS 4096 // h*w per image
#define NSTEP 19     // KP/32
#define GRID 9216    // 8 xcd * 8 pgrp * 8 r * 18 nt ; tiles (M/64)x(N/64)
#define CHUNKS_PER_ROW 76                    // KP/8
#define ACHUNKS (MM * CHUNKS_PER_ROW)        // 2,490,368
#define ABLOCKS (ACHUNKS / 256)              // 9728
#define BCHUNKS (NN * CHUNKS_PER_ROW)        // 87552
#define BBLOCKS ((BCHUNKS + 255) / 256)      // 342

#define AS1 __attribute__((address_space(1)))
#define AS3 __attribute__((address_space(3)))

// ---------------- helpers ----------------

__device__ __forceinline__ void cubic_taps(int dst, float* w, int* idx) {
    const float A = -0.75f;
    float src = (float)dst * 0.25f - 0.25f;   // (dst+0.5)*16/64 - 0.5
    int x0 = (int)floorf(src);
    #pragma unroll
    for (int k = -1; k <= 2; ++k) {
        int i = x0 + k;
        int ic = i < 0 ? 0 : (i > 15 ? 15 : i);
        float d = fabsf(src - (float)i);
        float wt;
        if (d <= 1.0f)      wt = ((A + 2.0f) * d - (A + 3.0f)) * d * d + 1.0f;
        else if (d < 2.0f)  wt = ((A * d - 5.0f * A) * d + 8.0f * A) * d - 4.0f * A;
        else                wt = 0.0f;
        w[k + 1] = wt;
        idx[k + 1] = ic;
    }
}

__device__ __forceinline__ void cvt_chunk(const float* __restrict__ src,
                                          ushort_t* __restrict__ dst, int c) {
    int row = c / CHUNKS_PER_ROW;
    int k0 = (c - row * CHUNKS_PER_ROW) * 8;
    const float* g = src + (size_t)row * KK + k0;
    bf16x8 v;
    if (k0 + 8 <= KK) {
        f32x4 a = *(const f32x4*)g;
        f32x4 b = *(const f32x4*)(g + 4);
        #pragma unroll
        for (int e = 0; e < 4; ++e) { v[e] = (__bf16)a[e]; v[e + 4] = (__bf16)b[e]; }
    } else {
        #pragma unroll
        for (int e = 0; e < 8; ++e)
            v[e] = (k0 + e < KK) ? (__bf16)g[e] : (__bf16)0.f;
    }
    *(bf16x8*)(dst + (size_t)row * KP + k0) = v;
}

// ---------------- prep: cvt A + cvt B (fp32->bf16, pad) + pos table (+bias) ----------------

__global__ void prep_kernel(const float* __restrict__ pv, ushort_t* __restrict__ pvb,
                            const float* __restrict__ wp, ushort_t* __restrict__ wb,
                            const float* __restrict__ pt, const float* __restrict__ bias,
                            float* __restrict__ pos) {
    int b = blockIdx.x;
    if (b < ABLOCKS) {
        cvt_chunk(pv, pvb, b * 256 + threadIdx.x);
    } else if (b < ABLOCKS + BBLOCKS) {
        int c = (b - ABLOCKS) * 256 + threadIdx.x;
        if (c < BCHUNKS) cvt_chunk(wp, wb, c);
    } else {
        // pos row (rearranged) with bias folded in
        int n = b - (ABLOCKS + BBLOCKS); // 0..4095
        int h = ((n >> 7) << 1) | ((n >> 1) & 1);
        int w = (((n >> 2) & 31) << 1) | (n & 1);
        float wh[4], ww[4];
        int ih[4], iw[4];
        cubic_taps(h, wh, ih);
        cubic_taps(w, ww, iw);
        const f32x4* pt4 = (const f32x4*)pt;
        const f32x4* bias4 = (const f32x4*)bias;
        for (int j = threadIdx.x; j < NN / 4; j += blockDim.x) {
            f32x4 s = bias4[j];
            #pragma unroll
            for (int a = 0; a < 4; ++a) {
                #pragma unroll
                for (int bq = 0; bq < 4; ++bq) {
                    float wt = wh[a] * ww[bq];
                    f32x4 vv = pt4[(ih[a] * 16 + iw[bq]) * (NN / 4) + j];
                    s.x += wt * vv.x; s.y += wt * vv.y; s.z += wt * vv.z; s.w += wt * vv.w;
                }
            }
            ((f32x4*)pos)[(size_t)n * (NN / 4) + j] = s;
        }
    }
}

// ---------------- barrier-free bf16 MFMA GEMM + pos epilogue ----------------
// ONE WAVE per block, 64x64 tile, wave-private LDS (16KB: 2buf x (4KB A + 4KB B)).
// Zero s_barrier: within a wave, s_waitcnt vmcnt(N) alone makes global_load_lds
// data readable; buffer reuse is ordered by the compiler's lgkm waits before the
// MFMAs that consume prior ds_reads. 10 free-running waves/CU hide each other's
// latency (12 rounds showed every barriered variant pins at ~93us with all pipes
// idle -- the 2 barriers/K-step were the binder hypothesis).

__global__ __launch_bounds__(64)
void gemm_kernel(const ushort_t* __restrict__ Abf,
                 const ushort_t* __restrict__ Bbf,
                 const float* __restrict__ pos,
                 float* __restrict__ out) {
    __shared__ __align__(16) ushort_t lA[2][64 * 32]; // 4KB/buf, 16B slots swizzled
    __shared__ __align__(16) ushort_t lB[2][64 * 32];

    const int t = threadIdx.x;   // 0..63 (one wave)
    const int lm = t & 15;
    const int lq = t >> 4;       // 0..3

    // reuse-aware bijective swizzle: 9216 = 8 xcd * 8 pgrp * 8 r * 18 nt.
    // pos panel p = pgrp*8+xcd (64 panels x 64 rows, 295KB each, L2-resident);
    // A panel mt = r*64+p shared by the 18 consecutive nt blocks.
    int blk = (int)blockIdx.x;
    int xcd = blk & 7;
    int local = blk >> 3;          // 0..1151
    int pgrp = local / 144;        // 0..7
    int rem = local - pgrp * 144;  // 0..143
    int r  = rem / 18;             // 0..7
    int nt = rem - r * 18;         // 0..17
    int p  = pgrp * 8 + xcd;       // 0..63
    int mt = r * 64 + p;           // 0..511
    const int bm = mt * 64;
    const int bn = nt * 64;

    f32x4 acc[4][4] = {};

    auto stage = [&](int ks, int buf) { // 8 loads: 4 A + 4 B (64 rows x 64B each)
        const int k0 = ks * 32;
        #pragma unroll
        for (int j = 0; j < 4; ++j) {
            int idx = j * 64 + t;              // 0..255
            int row = idx >> 2;
            int slot = idx & 3;
            int khi = slot ^ ((row >> 1) & 3); // inverse swizzle on SOURCE (lds dest linear)
            const ushort_t* gA = Abf + (size_t)(bm + row) * KP + k0 + khi * 8;
            const ushort_t* gB = Bbf + (size_t)(bn + row) * KP + k0 + khi * 8;
            ushort_t* lAp = &lA[buf][(size_t)(idx & ~63) * 8]; // wave-uniform base, 16B/lane
            ushort_t* lBp = &lB[buf][(size_t)(idx & ~63) * 8];
            __builtin_amdgcn_global_load_lds(
                (const AS1 void*)gA, (AS3 void*)lAp, 16, 0, 0);
            __builtin_amdgcn_global_load_lds(
                (const AS1 void*)gB, (AS3 void*)lBp, 16, 0, 0);
        }
    };

    stage(0, 0); // prologue: tile 0 in flight (8 loads)

    for (int ks = 0; ks < NSTEP; ++ks) {
        const int cur = ks & 1;

        if (ks + 1 < NSTEP) {
            stage(ks + 1, cur ^ 1);                          // 8 more in flight
            asm volatile("s_waitcnt vmcnt(8)" ::: "memory"); // tile ks landed; ks+1 flies
        } else {
            asm volatile("s_waitcnt vmcnt(0)" ::: "memory");
        }
        __builtin_amdgcn_sched_barrier(0); // keep ds_reads below the vmcnt gate

        bf16x8 af[4], bfr[4];
        #pragma unroll
        for (int mi = 0; mi < 4; ++mi) {
            int row = mi * 16 + lm;
            int slot = lq ^ ((row >> 1) & 3);
            af[mi] = *(const bf16x8*)(&lA[cur][row * 32 + slot * 8]);
        }
        #pragma unroll
        for (int ni = 0; ni < 4; ++ni) {
            int row = ni * 16 + lm;
            int slot = lq ^ ((row >> 1) & 3);
            bfr[ni] = *(const bf16x8*)(&lB[cur][row * 32 + slot * 8]);
        }
        #pragma unroll
        for (int mi = 0; mi < 4; ++mi)
            #pragma unroll
            for (int ni = 0; ni < 4; ++ni)
                acc[mi][ni] = __builtin_amdgcn_mfma_f32_16x16x32_bf16(
                    bfr[ni], af[mi], acc[mi][ni], 0, 0, 0); // swapped -> col-quad C layout
        // no barrier: compiler's lgkm waits before the MFMAs retire all ds_reads
        // of buf[cur] before the next restage of buf[cur] can issue (in-order wave).
    }

    // epilogue: swapped C-layout -> lane holds out[m][nb..nb+3]; bias folded in pos
    #pragma unroll
    for (int mi = 0; mi < 4; ++mi) {
        int m = bm + mi * 16 + lm;
        const float* posrow = pos + (size_t)(m & (POSROWS - 1)) * NN;
        float* outrow = out + (size_t)m * NN;
        #pragma unroll
        for (int ni = 0; ni < 4; ++ni) {
            int nb = bn + ni * 16 + lq * 4;
            f32x4 pv4 = *(const f32x4*)(posrow + nb);
            f32x4 v = acc[mi][ni];
            v.x += pv4.x; v.y += pv4.y; v.z += pv4.z; v.w += pv4.w;
            *(f32x4*)(outrow + nb) = v;
        }
    }
}

// ---------------- fallback (ws too small): naive fp32 ----------------

__global__ void fb_kernel(const float* __restrict__ A, const float* __restrict__ W,
                          const float* __restrict__ bias, const float* __restrict__ pt,
                          float* __restrict__ out) {
    __shared__ float sA[16][17], sB[16][17];
    int ty = threadIdx.y, tx = threadIdx.x;
    int row = blockIdx.y * 16 + ty; // M
    int col = blockIdx.x * 16 + tx; // N
    float acc = 0.f;
    for (int k0 = 0; k0 < KK; k0 += 16) {
        int ka = k0 + tx;
        sA[ty][tx] = (ka < KK) ? A[(size_t)row * KK + ka] : 0.f;
        sB[ty][tx] = (ka < KK) ? W[(size_t)(blockIdx.x * 16 + ty) * KK + ka] : 0.f;
        __syncthreads();
        #pragma unroll
        for (int kk = 0; kk < 16; ++kk)
            acc += sA[ty][kk] * sB[tx][kk];
        __syncthreads();
    }
    int n = row & (POSROWS - 1);
    int h = ((n >> 7) << 1) | ((n >> 1) & 1);
    int w = (((n >> 2) & 31) << 1) | (n & 1);
    float wh[4], ww[4]; int ih[4], iw[4];
    cubic_taps(h, wh, ih);
    cubic_taps(w, ww, iw);
    float pq = 0.f;
    #pragma unroll
    for (int a = 0; a < 4; ++a) {
        float rs = 0.f;
        #pragma unroll
        for (int b = 0; b < 4; ++b)
            rs += ww[b] * pt[(ih[a] * 16 + iw[b]) * NN + col];
        pq += wh[a] * rs;
    }
    out[(size_t)row * NN + col] = acc + bias[col] + pq;
}

// ---------------- launch ----------------

extern "C" void kernel_launch(void* const* d_in, const int* in_sizes, int n_in,
                              void* d_out, int out_size, void* d_ws, size_t ws_size,
                              hipStream_t stream) {
    const float* pv   = (const float*)d_in[0]; // (32768, 588)
    const float* wp   = (const float*)d_in[1]; // (1152, 588)
    const float* bias = (const float*)d_in[2]; // (1152,)
    const float* pt   = (const float*)d_in[3]; // (256, 1152)
    float* out = (float*)d_out;

    const size_t pos_bytes = (size_t)POSROWS * NN * 4;   // 18,874,368
    const size_t pvb_bytes = (size_t)MM * KP * 2;        // 39,845,888
    const size_t wb_bytes  = (size_t)NN * KP * 2;        //  1,400,832
    const size_t need = pos_bytes + pvb_bytes + wb_bytes;

    if (ws_size >= need) {
        float* pos = (float*)d_ws;
        ushort_t* pvb = (ushort_t*)((char*)d_ws + pos_bytes);
        ushort_t* wb  = (ushort_t*)((char*)d_ws + pos_bytes + pvb_bytes);

        prep_kernel<<<ABLOCKS + BBLOCKS + POSROWS, 256, 0, stream>>>(
            pv, pvb, wp, wb, pt, bias, pos);
        gemm_kernel<<<GRID, 64, 0, stream>>>(pvb, wb, pos, out);
    } else {
        fb_kernel<<<dim3(NN / 16, MM / 16), dim3(16, 16), 0, stream>>>(pv, wp, bias, pt, out);
    }
}

// Round 15
// 160.833 us; speedup vs baseline: 1.0039x; 1.0039x over previous
//
#include <hip/hip_runtime.h>

typedef unsigned short ushort_t;
typedef unsigned int uint_t;

typedef __bf16 bf16x8 __attribute__((ext_vector_type(8)));
typedef float f32x4 __attribute__((ext_vector_type(4)));

#define KK 588       // true K
#define KP 608       // padded K (19 * 32)
#define NN 1152      // N (output cols)
#define MM 32768     // M (output rows)
#define POSROWS 4096 // h*w per image
#define NSTEP 19     // KP/32
#define GRID 2304    // 8 xcd * 4 pp * 9 nt * 8 r
#define CHUNKS_PER_ROW 76                    // KP/8
#define ACHUNKS (MM * CHUNKS_PER_ROW)        // 2,490,368
#define ABLOCKS (ACHUNKS / 256)              // 9728
#define BCHUNKS (NN * CHUNKS_PER_ROW)        // 87552
#define BBLOCKS ((BCHUNKS + 255) / 256)      // 342

#define AS1 __attribute__((address_space(1)))
#define AS3 __attribute__((address_space(3)))

// ---------------- helpers ----------------

__device__ __forceinline__ void cubic_taps(int dst, float* w, int* idx) {
    const float A = -0.75f;
    float src = (float)dst * 0.25f - 0.25f;   // (dst+0.5)*16/64 - 0.5
    int x0 = (int)floorf(src);
    #pragma unroll
    for (int k = -1; k <= 2; ++k) {
        int i = x0 + k;
        int ic = i < 0 ? 0 : (i > 15 ? 15 : i);
        float d = fabsf(src - (float)i);
        float wt;
        if (d <= 1.0f)      wt = ((A + 2.0f) * d - (A + 3.0f)) * d * d + 1.0f;
        else if (d < 2.0f)  wt = ((A * d - 5.0f * A) * d + 8.0f * A) * d - 4.0f * A;
        else                wt = 0.0f;
        w[k + 1] = wt;
        idx[k + 1] = ic;
    }
}

__device__ __forceinline__ void cvt_chunk(const float* __restrict__ src,
                                          ushort_t* __restrict__ dst, int c) {
    int row = c / CHUNKS_PER_ROW;
    int k0 = (c - row * CHUNKS_PER_ROW) * 8;
    const float* g = src + (size_t)row * KK + k0;
    bf16x8 v;
    if (k0 + 8 <= KK) {
        f32x4 a = *(const f32x4*)g;
        f32x4 b = *(const f32x4*)(g + 4);
        #pragma unroll
        for (int e = 0; e < 4; ++e) { v[e] = (__bf16)a[e]; v[e + 4] = (__bf16)b[e]; }
    } else {
        #pragma unroll
        for (int e = 0; e < 8; ++e)
            v[e] = (k0 + e < KK) ? (__bf16)g[e] : (__bf16)0.f;
    }
    *(bf16x8*)(dst + (size_t)row * KP + k0) = v;
}

// ---------------- prep: cvt A + cvt B (fp32->bf16, pad) + pos table (+bias) ----------------

__global__ void prep_kernel(const float* __restrict__ pv, ushort_t* __restrict__ pvb,
                            const float* __restrict__ wp, ushort_t* __restrict__ wb,
                            const float* __restrict__ pt, const float* __restrict__ bias,
                            float* __restrict__ pos) {
    int b = blockIdx.x;
    if (b < ABLOCKS) {
        cvt_chunk(pv, pvb, b * 256 + threadIdx.x);
    } else if (b < ABLOCKS + BBLOCKS) {
        int c = (b - ABLOCKS) * 256 + threadIdx.x;
        if (c < BCHUNKS) cvt_chunk(wp, wb, c);
    } else {
        // pos row (rearranged) with bias folded in
        int n = b - (ABLOCKS + BBLOCKS); // 0..4095
        int h = ((n >> 7) << 1) | ((n >> 1) & 1);
        int w = (((n >> 2) & 31) << 1) | (n & 1);
        float wh[4], ww[4];
        int ih[4], iw[4];
        cubic_taps(h, wh, ih);
        cubic_taps(w, ww, iw);
        const f32x4* pt4 = (const f32x4*)pt;
        const f32x4* bias4 = (const f32x4*)bias;
        for (int j = threadIdx.x; j < NN / 4; j += blockDim.x) {
            f32x4 s = bias4[j];
            #pragma unroll
            for (int a = 0; a < 4; ++a) {
                #pragma unroll
                for (int bq = 0; bq < 4; ++bq) {
                    float wt = wh[a] * ww[bq];
                    f32x4 vv = pt4[(ih[a] * 16 + iw[bq]) * (NN / 4) + j];
                    s.x += wt * vv.x; s.y += wt * vv.y; s.z += wt * vv.z; s.w += wt * vv.w;
                }
            }
            ((f32x4*)pos)[(size_t)n * (NN / 4) + j] = s;
        }
    }
}

// ---------------- whole-panel-resident bf16 MFMA GEMM ----------------
// 128x128 tile, 4 waves. The ENTIRE A-panel (128 x 608 bf16 = 152KB) is DMA'd
// into LDS once (step-major [19][128][32], each slab = proven conflict-free
// swizzled layout). One vmcnt(0)+barrier total. K-loop: NO staging, NO
// barriers -- 4 ds_read (A frag, prefetched 1 step) + 4 direct global loads
// (B frag from L2-hot 1.4MB B, prefetched 1 step) + 16 MFMA per step.
// R14 bug fixed: after the s=16 iteration the pipeline leaves step 18 in
// Ac/Bc (body(17) prefetches into Ac/Bc), so the final MFMA consumes Ac/Bc.

__global__ __launch_bounds__(256)
void gemm_kernel(const ushort_t* __restrict__ Abf,
                 const ushort_t* __restrict__ Bbf,
                 const float* __restrict__ pos,
                 float* __restrict__ out) {
    __shared__ __align__(16) ushort_t lA[NSTEP * 128 * 32]; // 155,648 B

    const int t = threadIdx.x;
    const int lane = t & 63;
    const int lm = lane & 15;
    const int lq = lane >> 4;
    const int wid = t >> 6;
    const int wm = wid >> 1, wn = wid & 1;

    // reuse-aware bijective swizzle (R7-proven: FETCH 61MB)
    int blk = (int)blockIdx.x;
    int xcd = blk & 7;
    int local = blk >> 3;        // 0..287
    int pp = local / 72;         // 0..3
    int rem = local - pp * 72;   // 0..71
    int nt = rem >> 3;           // 0..8
    int r  = rem & 7;            // 0..7
    int p  = pp * 8 + xcd;       // 0..31
    int mt = r * 32 + p;         // 0..255
    const int bm = mt * 128;
    const int bn = nt * 128;

    f32x4 acc[4][4] = {};

    // ---- one-shot panel DMA: 38 chunks/thread, step-major dest ----
    // dest chunk idx -> (s = idx>>9, row = (idx>>2)&127, slot = idx&3)
    // source k-chunk c = s*4 + (slot ^ ((row>>1)&3))  [inverse of read swizzle]
    #pragma unroll
    for (int j = 0; j < 38; ++j) {
        int idx = j * 256 + t;
        int s = idx >> 9;
        int row = (idx >> 2) & 127;
        int slot = idx & 3;
        int c = s * 4 + (slot ^ ((row >> 1) & 3));
        const ushort_t* g = Abf + (size_t)(bm + row) * KP + c * 8;
        ushort_t* lp = lA + (size_t)(idx & ~63) * 8; // wave-uniform base, 16B/lane
        __builtin_amdgcn_global_load_lds((const AS1 void*)g, (AS3 void*)lp, 16, 0, 0);
    }

    // B fragment direct load (row-major; per row 64B contiguous, L2-hot)
    auto ldB = [&](int s, int ni) -> bf16x8 {
        int row = wn * 64 + ni * 16 + lm;
        return *(const bf16x8*)(Bbf + (size_t)(bn + row) * KP + s * 32 + lq * 8);
    };
    // A fragment from resident panel (swizzled slab, 0-conflict per R7)
    auto rdA = [&](int s, int mi) -> bf16x8 {
        int row = wm * 64 + mi * 16 + lm;
        int slot = lq ^ ((row >> 1) & 3);
        return *(const bf16x8*)(lA + ((size_t)(s * 128 + row) * 4 + slot) * 8);
    };

    bf16x8 Ac[4], An[4], Bc[4], Bn[4];

    // B step-0 loads ride behind the panel DMA; one drain for everything.
    #pragma unroll
    for (int ni = 0; ni < 4; ++ni) Bc[ni] = ldB(0, ni);
    asm volatile("s_waitcnt vmcnt(0)" ::: "memory"); // panel + B0 landed
    __builtin_amdgcn_s_barrier();                    // cross-wave LDS visibility
    __builtin_amdgcn_sched_barrier(0);
    #pragma unroll
    for (int mi = 0; mi < 4; ++mi) Ac[mi] = rdA(0, mi);
    asm volatile("s_waitcnt lgkmcnt(0)" ::: "memory");
    __builtin_amdgcn_sched_barrier(0);

    // K-loop: barrier-free, staging-free; prefetch depth 1 (A via ds, B via L2).
    #define STEP_BODY(S, AC, AN, BC, BN)                                        \
        {                                                                       \
            _Pragma("unroll")                                                   \
            for (int ni = 0; ni < 4; ++ni) BN[ni] = ldB((S) + 1, ni);           \
            _Pragma("unroll")                                                   \
            for (int mi = 0; mi < 4; ++mi) AN[mi] = rdA((S) + 1, mi);           \
            __builtin_amdgcn_sched_barrier(0);                                  \
            _Pragma("unroll")                                                   \
            for (int mi = 0; mi < 4; ++mi)                                      \
                _Pragma("unroll")                                               \
                for (int ni = 0; ni < 4; ++ni)                                  \
                    acc[mi][ni] = __builtin_amdgcn_mfma_f32_16x16x32_bf16(      \
                        BC[ni], AC[mi], acc[mi][ni], 0, 0, 0);                  \
            __builtin_amdgcn_sched_barrier(0);                                  \
            asm volatile("s_waitcnt vmcnt(0) lgkmcnt(0)" ::: "memory");         \
            __builtin_amdgcn_sched_barrier(0);                                  \
        }

    for (int s = 0; s < NSTEP - 1; s += 2) {
        STEP_BODY(s, Ac, An, Bc, Bn);         // consume s,   prefetch s+1 -> An/Bn
        if (s + 2 < NSTEP) {
            STEP_BODY(s + 1, An, Ac, Bn, Bc); // consume s+1, prefetch s+2 -> Ac/Bc
        }
    }
    // final step 18: body(17) prefetched step 18 into Ac/Bc (NOT An/Bn -- R14 bug)
    #pragma unroll
    for (int mi = 0; mi < 4; ++mi)
        #pragma unroll
        for (int ni = 0; ni < 4; ++ni)
            acc[mi][ni] = __builtin_amdgcn_mfma_f32_16x16x32_bf16(
                Bc[ni], Ac[mi], acc[mi][ni], 0, 0, 0);

    // epilogue: swapped C-layout -> lane holds out[m][nb..nb+3]; bias folded in pos
    const int M0 = bm + wm * 64;
    const int N0 = bn + wn * 64;
    #pragma unroll
    for (int mi = 0; mi < 4; ++mi) {
        int m = M0 + mi * 16 + lm;
        const float* posrow = pos + (size_t)(m & (POSROWS - 1)) * NN;
        float* outrow = out + (size_t)m * NN;
        #pragma unroll
        for (int ni = 0; ni < 4; ++ni) {
            int nb = N0 + ni * 16 + lq * 4;
            f32x4 pv4 = *(const f32x4*)(posrow + nb);
            f32x4 v = acc[mi][ni];
            v.x += pv4.x; v.y += pv4.y; v.z += pv4.z; v.w += pv4.w;
            *(f32x4*)(outrow + nb) = v;
        }
    }
}

// ---------------- fallback (ws too small): naive fp32 ----------------

__global__ void fb_kernel(const float* __restrict__ A, const float* __restrict__ W,
                          const float* __restrict__ bias, const float* __restrict__ pt,
                          float* __restrict__ out) {
    __shared__ float sA[16][17], sB[16][17];
    int ty = threadIdx.y, tx = threadIdx.x;
    int row = blockIdx.y * 16 + ty; // M
    int col = blockIdx.x * 16 + tx; // N
    float acc = 0.f;
    for (int k0 = 0; k0 < KK; k0 += 16) {
        int ka = k0 + tx;
        sA[ty][tx] = (ka < KK) ? A[(size_t)row * KK + ka] : 0.f;
        sB[ty][tx] = (ka < KK) ? W[(size_t)(blockIdx.x * 16 + ty) * KK + ka] : 0.f;
        __syncthreads();
        #pragma unroll
        for (int kk = 0; kk < 16; ++kk)
            acc += sA[ty][kk] * sB[tx][kk];
        __syncthreads();
    }
    int n = row & (POSROWS - 1);
    int h = ((n >> 7) << 1) | ((n >> 1) & 1);
    int w = (((n >> 2) & 31) << 1) | (n & 1);
    float wh[4], ww[4]; int ih[4], iw[4];
    cubic_taps(h, wh, ih);
    cubic_taps(w, ww, iw);
    float pq = 0.f;
    #pragma unroll
    for (int a = 0; a < 4; ++a) {
        float rs = 0.f;
        #pragma unroll
        for (int b = 0; b < 4; ++b)
            rs += ww[b] * pt[(ih[a] * 16 + iw[b]) * NN + col];
        pq += wh[a] * rs;
    }
    out[(size_t)row * NN + col] = acc + bias[col] + pq;
}

// ---------------- launch ----------------

extern "C" void kernel_launch(void* const* d_in, const int* in_sizes, int n_in,
                              void* d_out, int out_size, void* d_ws, size_t ws_size,
                              hipStream_t stream) {
    const float* pv   = (const float*)d_in[0]; // (32768, 588)
    const float* wp   = (const float*)d_in[1]; // (1152, 588)
    const float* bias = (const float*)d_in[2]; // (1152,)
    const float* pt   = (const float*)d_in[3]; // (256, 1152)
    float* out = (float*)d_out;

    const size_t pos_bytes = (size_t)POSROWS * NN * 4;   // 18,874,368
    const size_t pvb_bytes = (size_t)MM * KP * 2;        // 39,845,888
    const size_t wb_bytes  = (size_t)NN * KP * 2;        //  1,400,832
    const size_t need = pos_bytes + pvb_bytes + wb_bytes;

    if (ws_size >= need) {
        float* pos = (float*)d_ws;
        ushort_t* pvb = (ushort_t*)((char*)d_ws + pos_bytes);
        ushort_t* wb  = (ushort_t*)((char*)d_ws + pos_bytes + pvb_bytes);

        prep_kernel<<<ABLOCKS + BBLOCKS + POSROWS, 256, 0, stream>>>(
            pv, pvb, wp, wb, pt, bias, pos);
        gemm_kernel<<<GRID, 256, 0, stream>>>(pvb, wb, pos, out);
    } else {
        fb_kernel<<<dim3(NN / 16, MM / 16), dim3(16, 16), 0, stream>>>(pv, wp, bias, pt, out);
    }
}